// Round 1
// baseline (719.848 us; speedup 1.0000x reference)
//
#include <hip/hip_runtime.h>
#include <math.h>

#define KV_HEADS 8
#define Q_HEADS 32
#define HEAD 128
#define BLOCK_SIZE 128
#define CONST_VAL 10.0f
#define F32_TINY 1.1754943508222875e-38f

// One workgroup per (kv_head, sequence). 256 threads = 4 waves.
// Wave w handles positions [w*32, w*32+32) of each block; within a wave,
// half 0 (lanes 0-31) takes even offset, half 1 odd. Each half-wave loads a
// 128-float K/V row cooperatively as float4 (512B coalesced segments).
__global__ __launch_bounds__(256)
void flat_pa_kernel(const float* __restrict__ query,
                    const float* __restrict__ key_cache,
                    const float* __restrict__ value_cache,
                    const int*   __restrict__ block_list,
                    const float* __restrict__ block_bias,
                    float*       __restrict__ out,
                    int blocks_per_seq)
{
    const int kh   = blockIdx.x;          // kv head
    const int b    = blockIdx.y;          // sequence
    const int tid  = threadIdx.x;
    const int wave = tid >> 6;            // 0..3
    const int lane = tid & 63;
    const int half = lane >> 5;           // 0 or 1
    const int l32  = lane & 31;
    const int dbase = 4 * l32;            // this lane's head-dim slice

    const float scale = 0.08838834764831845f;  // 1/sqrt(128)

    // q fragments for the 4 q-heads sharing this kv head (scale folded in)
    float4 qf[4];
    const float* qrow = query + (size_t)b * (Q_HEADS * HEAD)
                              + (size_t)kh * 4 * HEAD + dbase;
    #pragma unroll
    for (int j = 0; j < 4; ++j) {
        float4 t = *reinterpret_cast<const float4*>(qrow + j * HEAD);
        qf[j] = make_float4(t.x * scale, t.y * scale, t.z * scale, t.w * scale);
    }

    float acc[4][4];                       // [q-head j][d-slice c]
    #pragma unroll
    for (int j = 0; j < 4; ++j)
        #pragma unroll
        for (int c = 0; c < 4; ++c) acc[j][c] = 0.f;
    float psum[4] = {0.f, 0.f, 0.f, 0.f};  // unnormalized softmax sums

    const int nb0 = b * blocks_per_seq;
    for (int i = 0; i < blocks_per_seq; ++i) {
        const int n = nb0 + i;
        const long long blk = block_list[n];
        const float* kbase = key_cache   + blk * (long long)(BLOCK_SIZE * KV_HEADS * HEAD) + kh * HEAD;
        const float* vbase = value_cache + blk * (long long)(BLOCK_SIZE * KV_HEADS * HEAD) + kh * HEAD;
        const float* bias  = block_bias + (long long)n * BLOCK_SIZE;

        #pragma unroll 4
        for (int it = 0; it < 16; ++it) {
            const int s = wave * 32 + 2 * it + half;
            const size_t roff = (size_t)s * (KV_HEADS * HEAD) + dbase;
            const float4 kv4 = *reinterpret_cast<const float4*>(kbase + roff);
            const float4 vv4 = *reinterpret_cast<const float4*>(vbase + roff);
            const float  bs  = bias[s];

            float part[4];
            #pragma unroll
            for (int j = 0; j < 4; ++j)
                part[j] = qf[j].x * kv4.x + qf[j].y * kv4.y
                        + qf[j].z * kv4.z + qf[j].w * kv4.w;

            // reduce within each 32-lane half (masks 1..16 stay in-half)
            #pragma unroll
            for (int m = 1; m <= 16; m <<= 1) {
                #pragma unroll
                for (int j = 0; j < 4; ++j)
                    part[j] += __shfl_xor(part[j], m, 64);
            }

            #pragma unroll
            for (int j = 0; j < 4; ++j) {
                const float p = __expf(part[j] + bs - CONST_VAL);
                psum[j]   += p;            // same value in all 32 lanes of half
                acc[j][0] += p * vv4.x;
                acc[j][1] += p * vv4.y;
                acc[j][2] += p * vv4.z;
                acc[j][3] += p * vv4.w;
            }
        }
    }

    // combine the two halves (same d-slice, disjoint positions)
    #pragma unroll
    for (int j = 0; j < 4; ++j) {
        #pragma unroll
        for (int c = 0; c < 4; ++c)
            acc[j][c] += __shfl_xor(acc[j][c], 32, 64);
        // each lane already holds its half's full psum -> xor32 = wave total
        psum[j] += __shfl_xor(psum[j], 32, 64);
    }

    // cross-wave reduction in LDS
    __shared__ float lds_acc[4][4][HEAD];  // [wave][j][d], 8 KB
    __shared__ float lds_sum[4][4];        // [wave][j]
    if (half == 0) {
        #pragma unroll
        for (int j = 0; j < 4; ++j)
            #pragma unroll
            for (int c = 0; c < 4; ++c)
                lds_acc[wave][j][dbase + c] = acc[j][c];
        if (l32 == 0) {
            #pragma unroll
            for (int j = 0; j < 4; ++j) lds_sum[wave][j] = psum[j];
        }
    }
    __syncthreads();

    // 512 outputs per WG, 2 per thread
    for (int o = tid; o < 4 * HEAD; o += 256) {
        const int j = o >> 7;
        const int d = o & 127;
        const float a = lds_acc[0][j][d] + lds_acc[1][j][d]
                      + lds_acc[2][j][d] + lds_acc[3][j][d];
        const float sum = lds_sum[0][j] + lds_sum[1][j]
                        + lds_sum[2][j] + lds_sum[3][j] + F32_TINY;
        out[(size_t)b * (Q_HEADS * HEAD) + (size_t)(kh * 4 + j) * HEAD + d] = a / sum;
    }
}

extern "C" void kernel_launch(void* const* d_in, const int* in_sizes, int n_in,
                              void* d_out, int out_size, void* d_ws, size_t ws_size,
                              hipStream_t stream) {
    const float* query       = (const float*)d_in[0];
    const float* key_cache   = (const float*)d_in[1];
    const float* value_cache = (const float*)d_in[2];
    const int*   block_list  = (const int*)d_in[3];
    // d_in[4] = block_mapping (one-hot; implied by contiguous grouping)
    const float* block_bias  = (const float*)d_in[5];
    // d_in[6] = block_groups (block i -> seq i / blocks_per_seq)
    float* out = (float*)d_out;

    const int B  = in_sizes[0] / (Q_HEADS * HEAD);
    const int NB = in_sizes[3];
    const int blocks_per_seq = NB / B;

    dim3 grid(KV_HEADS, B);
    flat_pa_kernel<<<grid, 256, 0, stream>>>(
        query, key_cache, value_cache, block_list, block_bias, out, blocks_per_seq);
}

// Round 2
// 438.846 us; speedup vs baseline: 1.6403x; 1.6403x over previous
//
#include <hip/hip_runtime.h>
#include <math.h>

#define KV_HEADS 8
#define Q_HEADS 32
#define HEAD 128
#define BLOCK_SIZE 128
#define CONST_VAL 10.0f
#define F32_TINY 1.1754943508222875e-38f
#define SPLIT 8

// ---------------------------------------------------------------------------
// Kernel 1: one WG per (kv_head, sequence, split). 256 threads = 4 waves.
// Processes blocks [sp*per, min((sp+1)*per, bps)) of the sequence and writes
// UNNORMALIZED partials (sum p*v over its positions, and sum p) to d_ws.
// Const-normalized softmax (p = exp(s - 10)) means partials merge by simple
// addition -- no online rescale needed.
// ---------------------------------------------------------------------------
__global__ __launch_bounds__(256)
void flat_pa_partial(const float* __restrict__ query,
                     const float* __restrict__ key_cache,
                     const float* __restrict__ value_cache,
                     const int*   __restrict__ block_list,
                     const float* __restrict__ block_bias,
                     float*       __restrict__ ws_acc,   // [KV][B][SPLIT][4][HEAD]
                     float*       __restrict__ ws_sum,   // [KV][B][SPLIT][4]
                     int B, int blocks_per_seq)
{
    const int kh   = blockIdx.x;          // kv head
    const int b    = blockIdx.y;          // sequence
    const int sp   = blockIdx.z;          // split
    const int tid  = threadIdx.x;
    const int wave = tid >> 6;            // 0..3
    const int lane = tid & 63;
    const int half = lane >> 5;           // 0 or 1
    const int l32  = lane & 31;
    const int dbase = 4 * l32;            // this lane's head-dim slice

    const float scale = 0.08838834764831845f;  // 1/sqrt(128)

    // q fragments for the 4 q-heads sharing this kv head (scale folded in)
    float4 qf[4];
    const float* qrow = query + (size_t)b * (Q_HEADS * HEAD)
                              + (size_t)kh * 4 * HEAD + dbase;
    #pragma unroll
    for (int j = 0; j < 4; ++j) {
        float4 t = *reinterpret_cast<const float4*>(qrow + j * HEAD);
        qf[j] = make_float4(t.x * scale, t.y * scale, t.z * scale, t.w * scale);
    }

    float acc[4][4];                       // [q-head j][d-slice c]
    #pragma unroll
    for (int j = 0; j < 4; ++j)
        #pragma unroll
        for (int c = 0; c < 4; ++c) acc[j][c] = 0.f;
    float psum[4] = {0.f, 0.f, 0.f, 0.f};  // unnormalized softmax sums

    const int per   = (blocks_per_seq + SPLIT - 1) / SPLIT;
    const int i0    = sp * per;
    const int i1    = min(i0 + per, blocks_per_seq);
    const int nb0   = b * blocks_per_seq;

    for (int i = i0; i < i1; ++i) {
        const int n = nb0 + i;
        const long long blk = block_list[n];
        const float* kbase = key_cache   + blk * (long long)(BLOCK_SIZE * KV_HEADS * HEAD) + kh * HEAD;
        const float* vbase = value_cache + blk * (long long)(BLOCK_SIZE * KV_HEADS * HEAD) + kh * HEAD;
        const float* bias  = block_bias + (long long)n * BLOCK_SIZE;

        #pragma unroll 4
        for (int it = 0; it < 16; ++it) {
            const int s = wave * 32 + 2 * it + half;
            const size_t roff = (size_t)s * (KV_HEADS * HEAD) + dbase;
            const float4 kv4 = *reinterpret_cast<const float4*>(kbase + roff);
            const float4 vv4 = *reinterpret_cast<const float4*>(vbase + roff);
            const float  bs  = bias[s];

            float part[4];
            #pragma unroll
            for (int j = 0; j < 4; ++j)
                part[j] = qf[j].x * kv4.x + qf[j].y * kv4.y
                        + qf[j].z * kv4.z + qf[j].w * kv4.w;

            // reduce within each 32-lane half (masks 1..16 stay in-half)
            #pragma unroll
            for (int m = 1; m <= 16; m <<= 1) {
                #pragma unroll
                for (int j = 0; j < 4; ++j)
                    part[j] += __shfl_xor(part[j], m, 64);
            }

            #pragma unroll
            for (int j = 0; j < 4; ++j) {
                const float p = __expf(part[j] + bs - CONST_VAL);
                psum[j]   += p;            // same value in all 32 lanes of half
                acc[j][0] += p * vv4.x;
                acc[j][1] += p * vv4.y;
                acc[j][2] += p * vv4.z;
                acc[j][3] += p * vv4.w;
            }
        }
    }

    // combine the two halves (same d-slice, disjoint positions)
    #pragma unroll
    for (int j = 0; j < 4; ++j) {
        #pragma unroll
        for (int c = 0; c < 4; ++c)
            acc[j][c] += __shfl_xor(acc[j][c], 32, 64);
        psum[j] += __shfl_xor(psum[j], 32, 64);
    }

    // cross-wave reduction in LDS
    __shared__ float lds_acc[4][4][HEAD];  // [wave][j][d], 8 KB
    __shared__ float lds_sum[4][4];        // [wave][j]
    if (half == 0) {
        #pragma unroll
        for (int j = 0; j < 4; ++j)
            #pragma unroll
            for (int c = 0; c < 4; ++c)
                lds_acc[wave][j][dbase + c] = acc[j][c];
        if (l32 == 0) {
            #pragma unroll
            for (int j = 0; j < 4; ++j) lds_sum[wave][j] = psum[j];
        }
    }
    __syncthreads();

    const size_t slot = ((size_t)kh * B + b) * SPLIT + sp;
    float* wa = ws_acc + slot * (4 * HEAD);
    for (int o = tid; o < 4 * HEAD; o += 256) {
        const int j = o >> 7;
        const int d = o & 127;
        wa[o] = lds_acc[0][j][d] + lds_acc[1][j][d]
              + lds_acc[2][j][d] + lds_acc[3][j][d];
    }
    if (tid < 4) {
        ws_sum[slot * 4 + tid] = lds_sum[0][tid] + lds_sum[1][tid]
                               + lds_sum[2][tid] + lds_sum[3][tid];
    }
}

// ---------------------------------------------------------------------------
// Kernel 2: merge SPLIT partials and normalize. One WG per (kv_head, seq).
// ---------------------------------------------------------------------------
__global__ __launch_bounds__(256)
void flat_pa_reduce(const float* __restrict__ ws_acc,
                    const float* __restrict__ ws_sum,
                    float*       __restrict__ out,
                    int B)
{
    const int kh  = blockIdx.x;
    const int b   = blockIdx.y;
    const int tid = threadIdx.x;

    const size_t base = ((size_t)kh * B + b) * SPLIT;

    for (int o = tid; o < 4 * HEAD; o += 256) {
        const int j = o >> 7;
        float a = 0.f, s = 0.f;
        #pragma unroll
        for (int sp = 0; sp < SPLIT; ++sp) {
            a += ws_acc[(base + sp) * (4 * HEAD) + o];
            s += ws_sum[(base + sp) * 4 + j];
        }
        s += F32_TINY;
        out[(size_t)b * (Q_HEADS * HEAD) + (size_t)(kh * 4 + (o >> 7)) * HEAD + (o & 127)] = a / s;
    }
}

// ---------------------------------------------------------------------------
// Fallback single-kernel path (used only if d_ws is too small): identical to
// the round-0 kernel.
// ---------------------------------------------------------------------------
__global__ __launch_bounds__(256)
void flat_pa_single(const float* __restrict__ query,
                    const float* __restrict__ key_cache,
                    const float* __restrict__ value_cache,
                    const int*   __restrict__ block_list,
                    const float* __restrict__ block_bias,
                    float*       __restrict__ out,
                    int blocks_per_seq)
{
    const int kh   = blockIdx.x;
    const int b    = blockIdx.y;
    const int tid  = threadIdx.x;
    const int wave = tid >> 6;
    const int lane = tid & 63;
    const int half = lane >> 5;
    const int l32  = lane & 31;
    const int dbase = 4 * l32;

    const float scale = 0.08838834764831845f;

    float4 qf[4];
    const float* qrow = query + (size_t)b * (Q_HEADS * HEAD)
                              + (size_t)kh * 4 * HEAD + dbase;
    #pragma unroll
    for (int j = 0; j < 4; ++j) {
        float4 t = *reinterpret_cast<const float4*>(qrow + j * HEAD);
        qf[j] = make_float4(t.x * scale, t.y * scale, t.z * scale, t.w * scale);
    }

    float acc[4][4];
    #pragma unroll
    for (int j = 0; j < 4; ++j)
        #pragma unroll
        for (int c = 0; c < 4; ++c) acc[j][c] = 0.f;
    float psum[4] = {0.f, 0.f, 0.f, 0.f};

    const int nb0 = b * blocks_per_seq;
    for (int i = 0; i < blocks_per_seq; ++i) {
        const int n = nb0 + i;
        const long long blk = block_list[n];
        const float* kbase = key_cache   + blk * (long long)(BLOCK_SIZE * KV_HEADS * HEAD) + kh * HEAD;
        const float* vbase = value_cache + blk * (long long)(BLOCK_SIZE * KV_HEADS * HEAD) + kh * HEAD;
        const float* bias  = block_bias + (long long)n * BLOCK_SIZE;

        #pragma unroll 4
        for (int it = 0; it < 16; ++it) {
            const int s = wave * 32 + 2 * it + half;
            const size_t roff = (size_t)s * (KV_HEADS * HEAD) + dbase;
            const float4 kv4 = *reinterpret_cast<const float4*>(kbase + roff);
            const float4 vv4 = *reinterpret_cast<const float4*>(vbase + roff);
            const float  bs  = bias[s];

            float part[4];
            #pragma unroll
            for (int j = 0; j < 4; ++j)
                part[j] = qf[j].x * kv4.x + qf[j].y * kv4.y
                        + qf[j].z * kv4.z + qf[j].w * kv4.w;
            #pragma unroll
            for (int m = 1; m <= 16; m <<= 1) {
                #pragma unroll
                for (int j = 0; j < 4; ++j)
                    part[j] += __shfl_xor(part[j], m, 64);
            }
            #pragma unroll
            for (int j = 0; j < 4; ++j) {
                const float p = __expf(part[j] + bs - CONST_VAL);
                psum[j]   += p;
                acc[j][0] += p * vv4.x;
                acc[j][1] += p * vv4.y;
                acc[j][2] += p * vv4.z;
                acc[j][3] += p * vv4.w;
            }
        }
    }

    #pragma unroll
    for (int j = 0; j < 4; ++j) {
        #pragma unroll
        for (int c = 0; c < 4; ++c)
            acc[j][c] += __shfl_xor(acc[j][c], 32, 64);
        psum[j] += __shfl_xor(psum[j], 32, 64);
    }

    __shared__ float lds_acc[4][4][HEAD];
    __shared__ float lds_sum[4][4];
    if (half == 0) {
        #pragma unroll
        for (int j = 0; j < 4; ++j)
            #pragma unroll
            for (int c = 0; c < 4; ++c)
                lds_acc[wave][j][dbase + c] = acc[j][c];
        if (l32 == 0) {
            #pragma unroll
            for (int j = 0; j < 4; ++j) lds_sum[wave][j] = psum[j];
        }
    }
    __syncthreads();

    for (int o = tid; o < 4 * HEAD; o += 256) {
        const int j = o >> 7;
        const int d = o & 127;
        const float a = lds_acc[0][j][d] + lds_acc[1][j][d]
                      + lds_acc[2][j][d] + lds_acc[3][j][d];
        const float sum = lds_sum[0][j] + lds_sum[1][j]
                        + lds_sum[2][j] + lds_sum[3][j] + F32_TINY;
        out[(size_t)b * (Q_HEADS * HEAD) + (size_t)(kh * 4 + j) * HEAD + d] = a / sum;
    }
}

extern "C" void kernel_launch(void* const* d_in, const int* in_sizes, int n_in,
                              void* d_out, int out_size, void* d_ws, size_t ws_size,
                              hipStream_t stream) {
    const float* query       = (const float*)d_in[0];
    const float* key_cache   = (const float*)d_in[1];
    const float* value_cache = (const float*)d_in[2];
    const int*   block_list  = (const int*)d_in[3];
    // d_in[4] = block_mapping (one-hot; implied by contiguous grouping)
    const float* block_bias  = (const float*)d_in[5];
    // d_in[6] = block_groups (block i -> seq i / blocks_per_seq)
    float* out = (float*)d_out;

    const int B  = in_sizes[0] / (Q_HEADS * HEAD);
    const int NB = in_sizes[3];
    const int blocks_per_seq = NB / B;

    const size_t acc_elems = (size_t)KV_HEADS * B * SPLIT * 4 * HEAD;
    const size_t sum_elems = (size_t)KV_HEADS * B * SPLIT * 4;
    const size_t need = (acc_elems + sum_elems) * sizeof(float);

    if (ws_size >= need) {
        float* ws_acc = (float*)d_ws;
        float* ws_sum = ws_acc + acc_elems;
        dim3 grid1(KV_HEADS, B, SPLIT);
        flat_pa_partial<<<grid1, 256, 0, stream>>>(
            query, key_cache, value_cache, block_list, block_bias,
            ws_acc, ws_sum, B, blocks_per_seq);
        dim3 grid2(KV_HEADS, B);
        flat_pa_reduce<<<grid2, 256, 0, stream>>>(ws_acc, ws_sum, out, B);
    } else {
        dim3 grid(KV_HEADS, B);
        flat_pa_single<<<grid, 256, 0, stream>>>(
            query, key_cache, value_cache, block_list, block_bias, out, blocks_per_seq);
    }
}

// Round 3
// 407.113 us; speedup vs baseline: 1.7682x; 1.0779x over previous
//
#include <hip/hip_runtime.h>
#include <math.h>

#define KV_HEADS 8
#define Q_HEADS 32
#define HEAD 128
#define BLOCK_SIZE 128
#define CONST_VAL 10.0f
#define F32_TINY 1.1754943508222875e-38f

// ---------------------------------------------------------------------------
// Kernel 1 (streaming layout): one WG per (seq b, split sp, head-group g).
// 256 threads = 4 waves; wave w owns kv-head kh = g*4 + w for ALL positions
// of the WG's blocks. Within a wave, half 0 (lanes 0-31) takes even position,
// half 1 odd; lane l32 holds head-dim slice [4*l32, 4*l32+4).
// Consequence: per position pair, the WG's 4 waves read 2 KB contiguous
// (heads g*4..g*4+3) of each 4 KB K/V row -> near-sequential 512 KB streams
// per block instead of 512 B chunks at 4 KB stride. Each wave owns its
// kv-head entirely -> no cross-wave LDS reduction needed.
// Writes UNNORMALIZED partials (sum p*v, sum p) to ws; const-normalized
// softmax (p = exp(s - 10)) merges partials by simple addition.
// ---------------------------------------------------------------------------
__global__ __launch_bounds__(256)
void flat_pa_stream(const float* __restrict__ query,
                    const float* __restrict__ key_cache,
                    const float* __restrict__ value_cache,
                    const int*   __restrict__ block_list,
                    const float* __restrict__ block_bias,
                    float*       __restrict__ ws_acc,  // [B*split*2][4w][4q][HEAD]
                    float*       __restrict__ ws_sum,  // [B*split*2][4w][4q]
                    int B, int blocks_per_seq, int split)
{
    const int g    = blockIdx.x & 1;      // head group (kh 0-3 or 4-7)
    const int sp   = blockIdx.x >> 1;     // split index
    const int b    = blockIdx.y;          // sequence
    const int tid  = threadIdx.x;
    const int wave = tid >> 6;            // 0..3
    const int lane = tid & 63;
    const int half = lane >> 5;           // 0 or 1 (even/odd position)
    const int l32  = lane & 31;
    const int dbase = 4 * l32;            // head-dim slice
    const int kh   = g * 4 + wave;        // this wave's kv head

    const float scale = 0.08838834764831845f;  // 1/sqrt(128)

    // q fragments for the 4 q-heads of this kv head (scale folded in)
    float4 qf[4];
    const float* qrow = query + (size_t)b * (Q_HEADS * HEAD)
                              + (size_t)kh * 4 * HEAD + dbase;
    #pragma unroll
    for (int j = 0; j < 4; ++j) {
        float4 t = *reinterpret_cast<const float4*>(qrow + j * HEAD);
        qf[j] = make_float4(t.x * scale, t.y * scale, t.z * scale, t.w * scale);
    }

    float acc[4][4];                       // [q-head j][d-slice c]
    #pragma unroll
    for (int j = 0; j < 4; ++j)
        #pragma unroll
        for (int c = 0; c < 4; ++c) acc[j][c] = 0.f;
    float psum[4] = {0.f, 0.f, 0.f, 0.f};

    const int per = (blocks_per_seq + split - 1) / split;
    const int i0  = sp * per;
    const int i1  = min(i0 + per, blocks_per_seq);
    const int nb0 = b * blocks_per_seq;
    const int khoff = kh * HEAD;

    for (int i = i0; i < i1; ++i) {
        const int n = nb0 + i;
        const long long blk = block_list[n];
        const float* kbase = key_cache   + blk * (long long)(BLOCK_SIZE * KV_HEADS * HEAD) + khoff;
        const float* vbase = value_cache + blk * (long long)(BLOCK_SIZE * KV_HEADS * HEAD) + khoff;
        const float* bias  = block_bias + (long long)n * BLOCK_SIZE;

        #pragma unroll 2
        for (int it = 0; it < BLOCK_SIZE / 2; ++it) {
            const int s = 2 * it + half;
            const size_t roff = (size_t)s * (KV_HEADS * HEAD) + dbase;
            const float4 kv4 = *reinterpret_cast<const float4*>(kbase + roff);
            const float4 vv4 = *reinterpret_cast<const float4*>(vbase + roff);
            const float  bs  = bias[s];

            float part[4];
            #pragma unroll
            for (int j = 0; j < 4; ++j)
                part[j] = qf[j].x * kv4.x + qf[j].y * kv4.y
                        + qf[j].z * kv4.z + qf[j].w * kv4.w;

            // reduce within each 32-lane half (masks 1..16 stay in-half)
            #pragma unroll
            for (int m = 1; m <= 16; m <<= 1) {
                #pragma unroll
                for (int j = 0; j < 4; ++j)
                    part[j] += __shfl_xor(part[j], m, 64);
            }

            #pragma unroll
            for (int j = 0; j < 4; ++j) {
                const float p = __expf(part[j] + bs - CONST_VAL);
                psum[j]   += p;
                acc[j][0] += p * vv4.x;
                acc[j][1] += p * vv4.y;
                acc[j][2] += p * vv4.z;
                acc[j][3] += p * vv4.w;
            }
        }
    }

    // combine the two halves (disjoint positions)
    #pragma unroll
    for (int j = 0; j < 4; ++j) {
        #pragma unroll
        for (int c = 0; c < 4; ++c)
            acc[j][c] += __shfl_xor(acc[j][c], 32, 64);
        psum[j] += __shfl_xor(psum[j], 32, 64);
    }

    // direct store: this wave owns kv-head kh. half0 stores j 0-1, half1 j 2-3.
    const size_t slot = (size_t)(b * split + sp) * 2 + g;
    float* wa = ws_acc + slot * (4 * 4 * HEAD) + (size_t)wave * (4 * HEAD);
    const int j0 = half * 2;
    #pragma unroll
    for (int t = 0; t < 2; ++t) {
        const int j = j0 + t;
        *reinterpret_cast<float4*>(wa + j * HEAD + dbase) =
            make_float4(acc[j][0], acc[j][1], acc[j][2], acc[j][3]);
    }
    if (l32 == 0) {
        ws_sum[slot * 16 + wave * 4 + j0]     = psum[j0];
        ws_sum[slot * 16 + wave * 4 + j0 + 1] = psum[j0 + 1];
    }
}

// ---------------------------------------------------------------------------
// Kernel 2: merge split partials and normalize. One WG per (kv_head, seq).
// ---------------------------------------------------------------------------
__global__ __launch_bounds__(256)
void flat_pa_reduce2(const float* __restrict__ ws_acc,
                     const float* __restrict__ ws_sum,
                     float*       __restrict__ out,
                     int B, int split)
{
    const int kh  = blockIdx.x;
    const int b   = blockIdx.y;
    const int tid = threadIdx.x;
    const int g   = kh >> 2;
    const int w   = kh & 3;

    for (int o = tid; o < 4 * HEAD; o += 256) {
        const int j = o >> 7;
        const int d = o & 127;
        float a = 0.f, s = 0.f;
        for (int sp = 0; sp < split; ++sp) {
            const size_t slot = (size_t)(b * split + sp) * 2 + g;
            a += ws_acc[slot * (4 * 4 * HEAD) + (size_t)w * (4 * HEAD) + o];
            s += ws_sum[slot * 16 + w * 4 + j];
        }
        s += F32_TINY;
        out[(size_t)b * (Q_HEADS * HEAD) + (size_t)(kh * 4 + j) * HEAD + d] = a / s;
    }
}

// ---------------------------------------------------------------------------
// Fallback single-kernel path (only if d_ws too small) - round-0 kernel.
// ---------------------------------------------------------------------------
__global__ __launch_bounds__(256)
void flat_pa_single(const float* __restrict__ query,
                    const float* __restrict__ key_cache,
                    const float* __restrict__ value_cache,
                    const int*   __restrict__ block_list,
                    const float* __restrict__ block_bias,
                    float*       __restrict__ out,
                    int blocks_per_seq)
{
    const int kh   = blockIdx.x;
    const int b    = blockIdx.y;
    const int tid  = threadIdx.x;
    const int wave = tid >> 6;
    const int lane = tid & 63;
    const int half = lane >> 5;
    const int l32  = lane & 31;
    const int dbase = 4 * l32;

    const float scale = 0.08838834764831845f;

    float4 qf[4];
    const float* qrow = query + (size_t)b * (Q_HEADS * HEAD)
                              + (size_t)kh * 4 * HEAD + dbase;
    #pragma unroll
    for (int j = 0; j < 4; ++j) {
        float4 t = *reinterpret_cast<const float4*>(qrow + j * HEAD);
        qf[j] = make_float4(t.x * scale, t.y * scale, t.z * scale, t.w * scale);
    }

    float acc[4][4];
    #pragma unroll
    for (int j = 0; j < 4; ++j)
        #pragma unroll
        for (int c = 0; c < 4; ++c) acc[j][c] = 0.f;
    float psum[4] = {0.f, 0.f, 0.f, 0.f};

    const int nb0 = b * blocks_per_seq;
    for (int i = 0; i < blocks_per_seq; ++i) {
        const int n = nb0 + i;
        const long long blk = block_list[n];
        const float* kbase = key_cache   + blk * (long long)(BLOCK_SIZE * KV_HEADS * HEAD) + kh * HEAD;
        const float* vbase = value_cache + blk * (long long)(BLOCK_SIZE * KV_HEADS * HEAD) + kh * HEAD;
        const float* bias  = block_bias + (long long)n * BLOCK_SIZE;

        #pragma unroll 4
        for (int it = 0; it < 16; ++it) {
            const int s = wave * 32 + 2 * it + half;
            const size_t roff = (size_t)s * (KV_HEADS * HEAD) + dbase;
            const float4 kv4 = *reinterpret_cast<const float4*>(kbase + roff);
            const float4 vv4 = *reinterpret_cast<const float4*>(vbase + roff);
            const float  bs  = bias[s];

            float part[4];
            #pragma unroll
            for (int j = 0; j < 4; ++j)
                part[j] = qf[j].x * kv4.x + qf[j].y * kv4.y
                        + qf[j].z * kv4.z + qf[j].w * kv4.w;
            #pragma unroll
            for (int m = 1; m <= 16; m <<= 1) {
                #pragma unroll
                for (int j = 0; j < 4; ++j)
                    part[j] += __shfl_xor(part[j], m, 64);
            }
            #pragma unroll
            for (int j = 0; j < 4; ++j) {
                const float p = __expf(part[j] + bs - CONST_VAL);
                psum[j]   += p;
                acc[j][0] += p * vv4.x;
                acc[j][1] += p * vv4.y;
                acc[j][2] += p * vv4.z;
                acc[j][3] += p * vv4.w;
            }
        }
    }

    #pragma unroll
    for (int j = 0; j < 4; ++j) {
        #pragma unroll
        for (int c = 0; c < 4; ++c)
            acc[j][c] += __shfl_xor(acc[j][c], 32, 64);
        psum[j] += __shfl_xor(psum[j], 32, 64);
    }

    __shared__ float lds_acc[4][4][HEAD];
    __shared__ float lds_sum[4][4];
    if (half == 0) {
        #pragma unroll
        for (int j = 0; j < 4; ++j)
            #pragma unroll
            for (int c = 0; c < 4; ++c)
                lds_acc[wave][j][dbase + c] = acc[j][c];
        if (l32 == 0) {
            #pragma unroll
            for (int j = 0; j < 4; ++j) lds_sum[wave][j] = psum[j];
        }
    }
    __syncthreads();

    for (int o = tid; o < 4 * HEAD; o += 256) {
        const int j = o >> 7;
        const int d = o & 127;
        const float a = lds_acc[0][j][d] + lds_acc[1][j][d]
                      + lds_acc[2][j][d] + lds_acc[3][j][d];
        const float sum = lds_sum[0][j] + lds_sum[1][j]
                        + lds_sum[2][j] + lds_sum[3][j] + F32_TINY;
        out[(size_t)b * (Q_HEADS * HEAD) + (size_t)(kh * 4 + j) * HEAD + d] = a / sum;
    }
}

extern "C" void kernel_launch(void* const* d_in, const int* in_sizes, int n_in,
                              void* d_out, int out_size, void* d_ws, size_t ws_size,
                              hipStream_t stream) {
    const float* query       = (const float*)d_in[0];
    const float* key_cache   = (const float*)d_in[1];
    const float* value_cache = (const float*)d_in[2];
    const int*   block_list  = (const int*)d_in[3];
    // d_in[4] = block_mapping (one-hot; implied by contiguous grouping)
    const float* block_bias  = (const float*)d_in[5];
    // d_in[6] = block_groups (block i -> seq i / blocks_per_seq)
    float* out = (float*)d_out;

    const int B  = in_sizes[0] / (Q_HEADS * HEAD);
    const int NB = in_sizes[3];
    const int blocks_per_seq = NB / B;

    // split so each WG handles ~2 blocks: B*split*2 WGs total (target ~2048)
    int split = (blocks_per_seq + 1) / 2;
    if (split < 1) split = 1;

    const size_t nslots    = (size_t)B * split * 2;
    const size_t acc_elems = nslots * 4 * 4 * HEAD;
    const size_t sum_elems = nslots * 16;
    const size_t need = (acc_elems + sum_elems) * sizeof(float);

    if (ws_size >= need) {
        float* ws_acc = (float*)d_ws;
        float* ws_sum = ws_acc + acc_elems;
        dim3 grid1(2 * split, B);
        flat_pa_stream<<<grid1, 256, 0, stream>>>(
            query, key_cache, value_cache, block_list, block_bias,
            ws_acc, ws_sum, B, blocks_per_seq, split);
        dim3 grid2(KV_HEADS, B);
        flat_pa_reduce2<<<grid2, 256, 0, stream>>>(ws_acc, ws_sum, out, B, split);
    } else {
        dim3 grid(KV_HEADS, B);
        flat_pa_single<<<grid, 256, 0, stream>>>(
            query, key_cache, value_cache, block_list, block_bias, out, blocks_per_seq);
    }
}